// Round 6
// baseline (360.910 us; speedup 1.0000x reference)
//
#include <hip/hip_runtime.h>
#include <math.h>

// ---------------------------------------------------------------------------
// B=1024, conv1d(3->64,k=5,pad=2) T=100, LSTM(64->128) 100 steps (MFMA),
// per-row epilogue (W1c tanh, W2, W0, LN, linear), tile to (14,14).
//
// LSTM: 32 blocks x 512 thr (8 waves). Block owns 32 batch rows = TWO
// independent 16-row streams (A,B) sharing weight registers and one barrier
// per step. Cross-stream ILP fills the MFMA-chain + transcendental-tail
// dependency bubbles that round-5's lockstep waves could not (active-CU
// issue floor ~1220cyc vs 3744 measured => ~2500cyc of stalls to absorb).
// h carried bf16 hi+lo (bf16x3); x bf16-hi only.
// ---------------------------------------------------------------------------

#define T_STEPS 100
#define LROW    208          // ushorts per LDS row (416 B, 16B-aligned)
#define PLANE   (16 * LROW)  // ushorts per [16][LROW] plane

// workspace byte offsets
#define OFF_WHI    0u          // 98304 ushort
#define OFF_WLO    196608u     // 98304 ushort
#define OFF_BIAS   393216u     // 512 f32
#define OFF_W1CT   395264u     // 16384 f32
#define OFF_W2T    460800u
#define OFF_W0T    526336u
#define OFF_LINWT  591872u
#define OFF_XHI    657408u     // 100*1024*64 ushort
#define OFF_HFIN   26871808u   // 1024*128 f32
// ws total needed: 27396096 B

typedef __attribute__((ext_vector_type(8))) short short8;
typedef __attribute__((ext_vector_type(4))) float f32x4;

__device__ __forceinline__ float frcp(float x) { return __builtin_amdgcn_rcpf(x); }
__device__ __forceinline__ float sigf(float x) { return frcp(1.f + __expf(-x)); }
__device__ __forceinline__ float tanhf_fast(float x) { return 2.f * frcp(1.f + __expf(-2.f * x)) - 1.f; }
__device__ __forceinline__ ushort f2bf(float f) {
    uint u = __float_as_uint(f);
    return (ushort)((u + 0x7fffu + ((u >> 16) & 1u)) >> 16);
}
__device__ __forceinline__ float bf2f(ushort h) { return __uint_as_float((uint)h << 16); }

// ---------------------------------------------------------------------------
// prep: pack LSTM weight B-fragments (hi/lo) + bias + epilogue transposes.
// ---------------------------------------------------------------------------
__global__ void prep_kernel(const float* __restrict__ w_ih, const float* __restrict__ w_hh,
                            const float* __restrict__ b_ih, const float* __restrict__ b_hh,
                            const float* __restrict__ W1, const float* __restrict__ W2,
                            const float* __restrict__ W0, const float* __restrict__ lin_w,
                            char* __restrict__ wsb) {
    ushort* whi   = (ushort*)(wsb + OFF_WHI);
    ushort* wlo   = (ushort*)(wsb + OFF_WLO);
    float*  biasv = (float*)(wsb + OFF_BIAS);
    float*  W1cT  = (float*)(wsb + OFF_W1CT);
    float*  W2T   = (float*)(wsb + OFF_W2T);
    float*  W0T   = (float*)(wsb + OFF_W0T);
    float*  linWT = (float*)(wsb + OFF_LINWT);

    int blk = blockIdx.x, tid = threadIdx.x;
    if (blk < 192) {
        int idx = blk * 512 + tid;
        int e = idx & 7;
        int l = (idx >> 3) & 63;
        int s = (idx >> 9) & 3;
        int rem = idx >> 11;           // w*6 + kt
        int kt = rem % 6, w = rem / 6;
        int g = s * 128 + 16 * w + (l & 15);
        int k = kt * 32 + (l >> 4) * 8 + e;
        float v = (k < 64) ? w_ih[g * 64 + k] : w_hh[g * 128 + (k - 64)];
        ushort hi = f2bf(v);
        whi[idx] = hi;
        wlo[idx] = f2bf(v - bf2f(hi));
    } else if (blk == 192) {
        biasv[tid] = b_ih[tid] + b_hh[tid];
    } else if (blk < 225) {
        int idx = (blk - 193) * 512 + tid;
        int f = idx >> 7, hh = idx & 127;
        W1cT[f * 128 + hh] = W1[hh * 256 + f] + W1[hh * 256 + 128 + f];
    } else if (blk < 257) {
        int idx = (blk - 225) * 512 + tid;
        int h = idx >> 7, f = idx & 127;
        W2T[h * 128 + f] = W2[f * 128 + h];
    } else if (blk < 289) {
        int idx = (blk - 257) * 512 + tid;
        int k = idx >> 7, f = idx & 127;
        W0T[k * 128 + f] = W0[f * 128 + k];
    } else {
        int idx = (blk - 289) * 512 + tid;
        int k = idx >> 7, f = idx & 127;
        linWT[k * 128 + f] = lin_w[f * 128 + k];
    }
}

// ---------------------------------------------------------------------------
// conv: agent = x[:,0] (B,3,100) -> relu(conv1d+b) -> xhi[t][b][k] bf16
// ---------------------------------------------------------------------------
__global__ __launch_bounds__(256) void conv_kernel(const float* __restrict__ x,
                                                   const float* __restrict__ conv_w,
                                                   const float* __restrict__ conv_b,
                                                   char* __restrict__ wsb) {
    ushort* xhi = (ushort*)(wsb + OFF_XHI);
    __shared__ float sx[3][104];
    __shared__ float sw[960];
    __shared__ float sb[64];
    int b = blockIdx.x, tid = threadIdx.x;

    for (int i = tid; i < 312; i += 256) {
        int c = i / 104, tp = i % 104;
        int t = tp - 2;
        sx[c][tp] = (t >= 0 && t < 100) ? x[b * 38400 + c * 100 + t] : 0.f;
    }
    for (int i = tid; i < 960; i += 256) sw[i] = conv_w[i];
    if (tid < 64) sb[tid] = conv_b[tid];
    __syncthreads();

    for (int i = tid; i < 6400; i += 256) {
        int t = i >> 6, k = i & 63;
        float a = sb[k];
#pragma unroll
        for (int c = 0; c < 3; ++c)
#pragma unroll
            for (int kk = 0; kk < 5; ++kk)
                a += sx[c][t + kk] * sw[k * 15 + c * 5 + kk];
        a = fmaxf(a, 0.f);
        xhi[t * 65536 + b * 64 + k] = f2bf(a);
    }
}

// ---------------------------------------------------------------------------
// lstm_mfma: 32 blocks x 512 threads, 2 independent 16-row streams per block.
// ---------------------------------------------------------------------------
__global__ __launch_bounds__(512)
void lstm_mfma(const char* __restrict__ wsro, char* __restrict__ wsb) {
    const ushort* whi   = (const ushort*)(wsro + OFF_WHI);
    const ushort* wlo   = (const ushort*)(wsro + OFF_WLO);
    const float*  biasv = (const float*)(wsro + OFF_BIAS);
    const ushort* xhi   = (const ushort*)(wsro + OFF_XHI);
    float* hfin = (float*)(wsb + OFF_HFIN);

    __shared__ ushort LA[2][2][16][LROW];   // stream A: [buf][hi/lo][row][col]
    __shared__ ushort LB[2][2][16][LROW];   // stream B

    int tid = threadIdx.x;
    int w = tid >> 6, l = tid & 63;
    int b0 = blockIdx.x * 32;

    // ---- weights pinned in regs (shared by both streams):
    //      x-part hi only (8 frags), h-part hi+lo (32 frags)
    short8 wx[2][4];                  // kt 0..1 (K 0..63)
    short8 wh[4][4], wl_[4][4];       // kt 2..5 (K 64..191)
#pragma unroll
    for (int ktx = 0; ktx < 2; ++ktx)
#pragma unroll
        for (int s = 0; s < 4; ++s)
            wx[ktx][s] = *(const short8*)(whi + (((w * 6 + ktx) * 4 + s) * 64 + l) * 8);
#pragma unroll
    for (int kth = 0; kth < 4; ++kth)
#pragma unroll
        for (int s = 0; s < 4; ++s) {
            int base = (((w * 6 + 2 + kth) * 4 + s) * 64 + l) * 8;
            wh[kth][s]  = *(const short8*)(whi + base);
            wl_[kth][s] = *(const short8*)(wlo + base);
        }

    int jl = 16 * w + (l & 15);
    float bv[4];
#pragma unroll
    for (int s = 0; s < 4; ++s) bv[s] = biasv[s * 128 + jl];

    int arow = l & 15;
    int g16  = (l >> 4) * 16;
    uint rowbase = (uint)arow * (LROW * 2);
    uint rswz    = (uint)(arow & 7) << 4;
    int hrow0 = (l >> 4) * 4;

    // x staging address (byte offset within a plane), swizzled
    int xr = tid >> 5;
    uint xw = ((uint)xr * (LROW * 2) + (uint)(tid & 31) * 4) ^ ((uint)(xr & 7) << 4);

    // h write offsets for r=0..3
    uint hwa[4];
#pragma unroll
    for (int r = 0; r < 4; ++r) {
        uint row = (uint)(hrow0 + r);
        hwa[r] = (row * (LROW * 2) + 128u + 2u * (uint)jl) ^ ((row & 7u) << 4);
    }

    float cstA[4] = {0.f, 0.f, 0.f, 0.f}, hregA[4] = {0.f, 0.f, 0.f, 0.f};
    float cstB[4] = {0.f, 0.f, 0.f, 0.f}, hregB[4] = {0.f, 0.f, 0.f, 0.f};

    // zero LDS (h regions must read 0 at t=0)
    for (int i = tid; i < 2 * 2 * PLANE; i += 512) {
        ((ushort*)LA)[i] = 0;
        ((ushort*)LB)[i] = 0;
    }

    // prologue: x(0) staged into buf0 of both streams, vxA/vxB hold x(1)
    size_t xoffA = (size_t)b0 * 64 + (size_t)tid * 2;
    size_t xoffB = xoffA + 1024;           // rows b0+16..b0+31
    uint vxA = *(const uint*)(xhi + xoffA);
    uint vxB = *(const uint*)(xhi + xoffB);
    __syncthreads();                       // zeros visible
    *(uint*)((char*)&LA[0][0][0][0] + xw) = vxA;
    *(uint*)((char*)&LB[0][0][0][0] + xw) = vxB;
    vxA = *(const uint*)(xhi + xoffA + 65536);
    vxB = *(const uint*)(xhi + xoffB + 65536);
    __syncthreads();                       // x(0) visible

    for (int t = 0; t < T_STEPS; ++t) {
        int p = t & 1;
        const char* phA = (const char*)&LA[p][0][0][0];
        const char* plA = (const char*)&LA[p][1][0][0];
        const char* phB = (const char*)&LB[p][0][0][0];
        const char* plB = (const char*)&LB[p][1][0][0];
        char* qhA = (char*)&LA[p ^ 1][0][0][0];
        char* qlA = (char*)&LA[p ^ 1][1][0][0];
        char* qhB = (char*)&LB[p ^ 1][0][0][0];
        char* qlB = (char*)&LB[p ^ 1][1][0][0];

        // TOP: stage x(t+1) from regs; issue prefetch x(t+2) early so the
        // barrier's vmcnt drain costs ~nothing.
        if (t < T_STEPS - 1) {
            *(uint*)(qhA + xw) = vxA;
            *(uint*)(qhB + xw) = vxB;
            int tn = (t + 2 < T_STEPS) ? t + 2 : T_STEPS - 1;
            vxA = *(const uint*)(xhi + xoffA + (size_t)tn * 65536);
            vxB = *(const uint*)(xhi + xoffB + (size_t)tn * 65536);
        }

        f32x4 aA[4], aB[4];
#pragma unroll
        for (int s = 0; s < 4; ++s) {
            aA[s] = (f32x4){bv[s], bv[s], bv[s], bv[s]};
            aB[s] = (f32x4){bv[s], bv[s], bv[s], bv[s]};
        }

        // x part (hi only), both streams   [8 independent chains overall]
#pragma unroll
        for (int ktx = 0; ktx < 2; ++ktx) {
            uint ra = (rowbase + (uint)ktx * 64 + g16) ^ rswz;
            short8 axA = *(const short8*)(phA + ra);
            short8 axB = *(const short8*)(phB + ra);
#pragma unroll
            for (int s = 0; s < 4; ++s) {
                aA[s] = __builtin_amdgcn_mfma_f32_16x16x32_bf16(axA, wx[ktx][s], aA[s], 0, 0, 0);
                aB[s] = __builtin_amdgcn_mfma_f32_16x16x32_bf16(axB, wx[ktx][s], aB[s], 0, 0, 0);
            }
        }
        // h part (hi*hi + hi*lo + lo*hi), both streams
#pragma unroll
        for (int kth = 0; kth < 4; ++kth) {
            uint ra = (rowbase + 128u + (uint)kth * 64 + g16) ^ rswz;
            short8 ahA = *(const short8*)(phA + ra);
            short8 alA = *(const short8*)(plA + ra);
            short8 ahB = *(const short8*)(phB + ra);
            short8 alB = *(const short8*)(plB + ra);
#pragma unroll
            for (int s = 0; s < 4; ++s) {
                aA[s] = __builtin_amdgcn_mfma_f32_16x16x32_bf16(ahA, wh[kth][s], aA[s], 0, 0, 0);
                aB[s] = __builtin_amdgcn_mfma_f32_16x16x32_bf16(ahB, wh[kth][s], aB[s], 0, 0, 0);
            }
#pragma unroll
            for (int s = 0; s < 4; ++s) {
                aA[s] = __builtin_amdgcn_mfma_f32_16x16x32_bf16(ahA, wl_[kth][s], aA[s], 0, 0, 0);
                aB[s] = __builtin_amdgcn_mfma_f32_16x16x32_bf16(ahB, wl_[kth][s], aB[s], 0, 0, 0);
            }
#pragma unroll
            for (int s = 0; s < 4; ++s) {
                aA[s] = __builtin_amdgcn_mfma_f32_16x16x32_bf16(alA, wh[kth][s], aA[s], 0, 0, 0);
                aB[s] = __builtin_amdgcn_mfma_f32_16x16x32_bf16(alB, wh[kth][s], aB[s], 0, 0, 0);
            }
        }

        // pointwise LSTM cell, both streams (independent chains)
#pragma unroll
        for (int r = 0; r < 4; ++r) {
            float giA = sigf(aA[0][r]);
            float gfA = sigf(aA[1][r]);
            float ggA = tanhf_fast(aA[2][r]);
            float goA = sigf(aA[3][r]);
            cstA[r] = gfA * cstA[r] + giA * ggA;
            hregA[r] = goA * tanhf_fast(cstA[r]);

            float giB = sigf(aB[0][r]);
            float gfB = sigf(aB[1][r]);
            float ggB = tanhf_fast(aB[2][r]);
            float goB = sigf(aB[3][r]);
            cstB[r] = gfB * cstB[r] + giB * ggB;
            hregB[r] = goB * tanhf_fast(cstB[r]);
        }

        if (t < T_STEPS - 1) {
            // stage h(t) hi/lo into next buffers
#pragma unroll
            for (int r = 0; r < 4; ++r) {
                float hvA = hregA[r];
                ushort hhA = f2bf(hvA);
                *(ushort*)(qhA + hwa[r]) = hhA;
                *(ushort*)(qlA + hwa[r]) = f2bf(hvA - bf2f(hhA));
                float hvB = hregB[r];
                ushort hhB = f2bf(hvB);
                *(ushort*)(qhB + hwa[r]) = hhB;
                *(ushort*)(qlB + hwa[r]) = f2bf(hvB - bf2f(hhB));
            }
            __syncthreads();
        }
    }

#pragma unroll
    for (int r = 0; r < 4; ++r) {
        hfin[(size_t)(b0 + hrow0 + r) * 128 + jl]      = hregA[r];
        hfin[(size_t)(b0 + 16 + hrow0 + r) * 128 + jl] = hregB[r];
    }
}

// ---------------------------------------------------------------------------
// post: per row: u=tanh(W1c@h); v=W2@u; res=W0@h+127v; LN; linear; tile 196x.
// ---------------------------------------------------------------------------
__global__ __launch_bounds__(128) void post_kernel(const char* __restrict__ wsb,
                                                   const float* __restrict__ ln_g,
                                                   const float* __restrict__ ln_b,
                                                   const float* __restrict__ lin_b,
                                                   float* __restrict__ out) {
    const float* hfinal = (const float*)(wsb + OFF_HFIN);
    const float* W1cT   = (const float*)(wsb + OFF_W1CT);
    const float* W2T    = (const float*)(wsb + OFF_W2T);
    const float* W0T    = (const float*)(wsb + OFF_W0T);
    const float* linWT  = (const float*)(wsb + OFF_LINWT);

    __shared__ float sh[128], su[128], sres[128], spart[4];
    int b = blockIdx.x, f = threadIdx.x;

    sh[f] = hfinal[(size_t)b * 128 + f];
    __syncthreads();

    float acc = 0.f;
#pragma unroll 4
    for (int k = 0; k < 128; ++k) acc += W1cT[k * 128 + f] * sh[k];
    su[f] = tanhf_fast(acc);
    __syncthreads();

    float v = 0.f, r0 = 0.f;
#pragma unroll 4
    for (int k = 0; k < 128; ++k) {
        v  += W2T[k * 128 + f] * su[k];
        r0 += W0T[k * 128 + f] * sh[k];
    }
    float res = r0 + 127.f * v;

    int lane = f & 63, wid = f >> 6;
    float s = res;
#pragma unroll
    for (int off = 32; off > 0; off >>= 1) s += __shfl_down(s, off);
    if (lane == 0) spart[wid] = s;
    __syncthreads();
    float mu = (spart[0] + spart[1]) * (1.f / 128.f);
    float d = res - mu;
    float s2 = d * d;
#pragma unroll
    for (int off = 32; off > 0; off >>= 1) s2 += __shfl_down(s2, off);
    if (lane == 0) spart[2 + wid] = s2;
    __syncthreads();
    float var = (spart[2] + spart[3]) * (1.f / 128.f);
    float rn = d * rsqrtf(var + 1e-5f) * ln_g[f] + ln_b[f];
    sres[f] = rn;
    __syncthreads();

    float o = lin_b[f];
#pragma unroll 4
    for (int k = 0; k < 128; ++k) o += linWT[k * 128 + f] * sres[k];

    float* op = out + (size_t)b * 196 * 128 + f;
#pragma unroll 4
    for (int i = 0; i < 196; ++i) op[i * 128] = o;
}

// ---------------------------------------------------------------------------
extern "C" void kernel_launch(void* const* d_in, const int* in_sizes, int n_in,
                              void* d_out, int out_size, void* d_ws, size_t ws_size,
                              hipStream_t stream) {
    const float* x      = (const float*)d_in[0];
    const float* conv_w = (const float*)d_in[1];
    const float* conv_b = (const float*)d_in[2];
    const float* w_ih   = (const float*)d_in[3];
    const float* w_hh   = (const float*)d_in[4];
    const float* b_ih   = (const float*)d_in[5];
    const float* b_hh   = (const float*)d_in[6];
    const float* W1     = (const float*)d_in[7];
    const float* W2     = (const float*)d_in[8];
    const float* W0     = (const float*)d_in[9];
    const float* ln_g   = (const float*)d_in[10];
    const float* ln_b   = (const float*)d_in[11];
    const float* lin_w  = (const float*)d_in[12];
    const float* lin_b  = (const float*)d_in[13];
    char* wsb  = (char*)d_ws;
    float* out = (float*)d_out;

    prep_kernel<<<dim3(321), dim3(512), 0, stream>>>(w_ih, w_hh, b_ih, b_hh,
                                                     W1, W2, W0, lin_w, wsb);
    conv_kernel<<<dim3(1024), dim3(256), 0, stream>>>(x, conv_w, conv_b, wsb);
    lstm_mfma<<<dim3(32), dim3(512), 0, stream>>>(wsb, wsb);
    post_kernel<<<dim3(1024), dim3(128), 0, stream>>>(wsb, ln_g, ln_b, lin_b, out);
}

// Round 7
// 193.890 us; speedup vs baseline: 1.8614x; 1.8614x over previous
//
#include <hip/hip_runtime.h>
#include <math.h>

// ---------------------------------------------------------------------------
// B=1024, conv1d(3->64,k=5,pad=2) T=100, LSTM(64->128) 100 steps (MFMA),
// per-row epilogue (W1c tanh, W2, W0, LN, linear), tile to (14,14).
//
// LSTM: 64 blocks x 512 thr (8 waves, 2/SIMD). Block owns 16 batch rows.
// Wave w owns gate-cols [16w,16w+16), 4 gates as 4 acc tiles -> pointwise is
// lane-local. Precision scheme (bf16x2 on h): gates = x_hi*Wx_hi
// + (h_hi + h_lo)*Wh_hi. h stays ~fp32 (recurrent path exact); only static
// weights are perturbed (<=2^-9 rel). 40 MFMA/wave/step (was 56 with x3) —
// r5 was ~58% MFMA-pipe-limited (2x56x19.4 = 2172 of 3744 cyc/step), so the
// lever is pipe work, not scheduling. r6's 2-stream spilled (WRITE_SIZE
// 512->896KB) — reverted.
// ---------------------------------------------------------------------------

#define T_STEPS 100
#define LROW    208          // ushorts per LDS row (416 B, 16B-aligned)
#define PLANE   (16 * LROW)  // ushorts per [16][LROW] plane

// workspace byte offsets
#define OFF_WHI    0u          // 98304 ushort
#define OFF_BIAS   393216u     // 512 f32
#define OFF_W1CT   395264u     // 16384 f32
#define OFF_W2T    460800u
#define OFF_W0T    526336u
#define OFF_LINWT  591872u
#define OFF_XHI    657408u     // 100*1024*64 ushort
#define OFF_HFIN   26871808u   // 1024*128 f32
// ws total needed: 27396096 B

typedef __attribute__((ext_vector_type(8))) short short8;
typedef __attribute__((ext_vector_type(4))) float f32x4;

__device__ __forceinline__ float frcp(float x) { return __builtin_amdgcn_rcpf(x); }
__device__ __forceinline__ float sigf(float x) { return frcp(1.f + __expf(-x)); }
__device__ __forceinline__ float tanhf_fast(float x) { return 2.f * frcp(1.f + __expf(-2.f * x)) - 1.f; }
__device__ __forceinline__ ushort f2bf(float f) {
    uint u = __float_as_uint(f);
    return (ushort)((u + 0x7fffu + ((u >> 16) & 1u)) >> 16);
}
__device__ __forceinline__ float bf2f(ushort h) { return __uint_as_float((uint)h << 16); }

// ---------------------------------------------------------------------------
// prep: pack LSTM weight B-fragments (hi) + bias + epilogue transposes.
// ---------------------------------------------------------------------------
__global__ void prep_kernel(const float* __restrict__ w_ih, const float* __restrict__ w_hh,
                            const float* __restrict__ b_ih, const float* __restrict__ b_hh,
                            const float* __restrict__ W1, const float* __restrict__ W2,
                            const float* __restrict__ W0, const float* __restrict__ lin_w,
                            char* __restrict__ wsb) {
    ushort* whi   = (ushort*)(wsb + OFF_WHI);
    float*  biasv = (float*)(wsb + OFF_BIAS);
    float*  W1cT  = (float*)(wsb + OFF_W1CT);
    float*  W2T   = (float*)(wsb + OFF_W2T);
    float*  W0T   = (float*)(wsb + OFF_W0T);
    float*  linWT = (float*)(wsb + OFF_LINWT);

    int blk = blockIdx.x, tid = threadIdx.x;
    if (blk < 192) {
        int idx = blk * 512 + tid;
        int e = idx & 7;
        int l = (idx >> 3) & 63;
        int s = (idx >> 9) & 3;
        int rem = idx >> 11;           // w*6 + kt
        int kt = rem % 6, w = rem / 6;
        int g = s * 128 + 16 * w + (l & 15);
        int k = kt * 32 + (l >> 4) * 8 + e;
        float v = (k < 64) ? w_ih[g * 64 + k] : w_hh[g * 128 + (k - 64)];
        whi[idx] = f2bf(v);
    } else if (blk == 192) {
        biasv[tid] = b_ih[tid] + b_hh[tid];
    } else if (blk < 225) {
        int idx = (blk - 193) * 512 + tid;
        int f = idx >> 7, hh = idx & 127;
        W1cT[f * 128 + hh] = W1[hh * 256 + f] + W1[hh * 256 + 128 + f];
    } else if (blk < 257) {
        int idx = (blk - 225) * 512 + tid;
        int h = idx >> 7, f = idx & 127;
        W2T[h * 128 + f] = W2[f * 128 + h];
    } else if (blk < 289) {
        int idx = (blk - 257) * 512 + tid;
        int k = idx >> 7, f = idx & 127;
        W0T[k * 128 + f] = W0[f * 128 + k];
    } else {
        int idx = (blk - 289) * 512 + tid;
        int k = idx >> 7, f = idx & 127;
        linWT[k * 128 + f] = lin_w[f * 128 + k];
    }
}

// ---------------------------------------------------------------------------
// conv: agent = x[:,0] (B,3,100) -> relu(conv1d+b) -> xhi[t][b][k] bf16
// ---------------------------------------------------------------------------
__global__ __launch_bounds__(256) void conv_kernel(const float* __restrict__ x,
                                                   const float* __restrict__ conv_w,
                                                   const float* __restrict__ conv_b,
                                                   char* __restrict__ wsb) {
    ushort* xhi = (ushort*)(wsb + OFF_XHI);
    __shared__ float sx[3][104];
    __shared__ float sw[960];
    __shared__ float sb[64];
    int b = blockIdx.x, tid = threadIdx.x;

    for (int i = tid; i < 312; i += 256) {
        int c = i / 104, tp = i % 104;
        int t = tp - 2;
        sx[c][tp] = (t >= 0 && t < 100) ? x[b * 38400 + c * 100 + t] : 0.f;
    }
    for (int i = tid; i < 960; i += 256) sw[i] = conv_w[i];
    if (tid < 64) sb[tid] = conv_b[tid];
    __syncthreads();

    for (int i = tid; i < 6400; i += 256) {
        int t = i >> 6, k = i & 63;
        float a = sb[k];
#pragma unroll
        for (int c = 0; c < 3; ++c)
#pragma unroll
            for (int kk = 0; kk < 5; ++kk)
                a += sx[c][t + kk] * sw[k * 15 + c * 5 + kk];
        a = fmaxf(a, 0.f);
        xhi[t * 65536 + b * 64 + k] = f2bf(a);
    }
}

// ---------------------------------------------------------------------------
// lstm_mfma: 64 blocks x 512 threads, weights pinned in regs, 1 barrier/step.
// ---------------------------------------------------------------------------
__global__ __launch_bounds__(512, 2)
void lstm_mfma(const char* __restrict__ wsro, char* __restrict__ wsb) {
    const ushort* whi   = (const ushort*)(wsro + OFF_WHI);
    const float*  biasv = (const float*)(wsro + OFF_BIAS);
    const ushort* xhi   = (const ushort*)(wsro + OFF_XHI);
    float* hfin = (float*)(wsb + OFF_HFIN);

    __shared__ ushort L[2][2][16][LROW];   // [buf][hi/lo][row][col]

    int tid = threadIdx.x;
    int w = tid >> 6, l = tid & 63;
    int b0 = blockIdx.x * 16;

    // ---- weights pinned in regs: x-part hi (8 frags), h-part hi (16 frags)
    short8 wx[2][4];                  // kt 0..1 (K 0..63)
    short8 wh[4][4];                  // kt 2..5 (K 64..191)
#pragma unroll
    for (int ktx = 0; ktx < 2; ++ktx)
#pragma unroll
        for (int s = 0; s < 4; ++s)
            wx[ktx][s] = *(const short8*)(whi + (((w * 6 + ktx) * 4 + s) * 64 + l) * 8);
#pragma unroll
    for (int kth = 0; kth < 4; ++kth)
#pragma unroll
        for (int s = 0; s < 4; ++s)
            wh[kth][s] = *(const short8*)(whi + (((w * 6 + 2 + kth) * 4 + s) * 64 + l) * 8);

    int jl = 16 * w + (l & 15);
    float bv[4];
#pragma unroll
    for (int s = 0; s < 4; ++s) bv[s] = biasv[s * 128 + jl];

    int arow = l & 15;
    int g16  = (l >> 4) * 16;
    uint rowbase = (uint)arow * (LROW * 2);
    uint rswz    = (uint)(arow & 7) << 4;
    int hrow0 = (l >> 4) * 4;

    // x staging address (byte offset within a plane), swizzled
    int xr = tid >> 5;
    uint xw = ((uint)xr * (LROW * 2) + (uint)(tid & 31) * 4) ^ ((uint)(xr & 7) << 4);

    // h write offsets for r=0..3
    uint hwa[4];
#pragma unroll
    for (int r = 0; r < 4; ++r) {
        uint row = (uint)(hrow0 + r);
        hwa[r] = (row * (LROW * 2) + 128u + 2u * (uint)jl) ^ ((row & 7u) << 4);
    }

    float cst[4]  = {0.f, 0.f, 0.f, 0.f};
    float hreg[4] = {0.f, 0.f, 0.f, 0.f};

    // zero LDS (h regions must read 0 at t=0)
    for (int i = tid; i < 2 * 2 * PLANE; i += 512) ((ushort*)L)[i] = 0;

    // prologue: x(0) staged into buf0, vx holds x(1)
    size_t xoff0 = (size_t)b0 * 64 + (size_t)tid * 2;
    uint vx = *(const uint*)(xhi + xoff0);
    __syncthreads();                       // zeros visible
    *(uint*)((char*)&L[0][0][0][0] + xw) = vx;
    vx = *(const uint*)(xhi + xoff0 + 65536);
    __syncthreads();                       // x(0) visible

    for (int t = 0; t < T_STEPS; ++t) {
        int p = t & 1;
        const char* ph = (const char*)&L[p][0][0][0];
        const char* pl = (const char*)&L[p][1][0][0];
        char* qh = (char*)&L[p ^ 1][0][0][0];
        char* ql = (char*)&L[p ^ 1][1][0][0];

        // TOP of step: stage x(t+1) from regs; issue prefetch x(t+2) so it
        // has the whole step before the barrier's vmcnt drain.
        if (t < T_STEPS - 1) {
            *(uint*)(qh + xw) = vx;
            int tn = (t + 2 < T_STEPS) ? t + 2 : T_STEPS - 1;
            vx = *(const uint*)(xhi + xoff0 + (size_t)tn * 65536);
        }

        f32x4 accA[4], accB[4];
#pragma unroll
        for (int s = 0; s < 4; ++s) {
            accA[s] = (f32x4){bv[s], bv[s], bv[s], bv[s]};
            accB[s] = (f32x4){0.f, 0.f, 0.f, 0.f};
        }

        // x part (hi only) -> accA   [chain depth 2]
#pragma unroll
        for (int ktx = 0; ktx < 2; ++ktx) {
            short8 ax = *(const short8*)(ph + ((rowbase + (uint)ktx * 64 + g16) ^ rswz));
#pragma unroll
            for (int s = 0; s < 4; ++s)
                accA[s] = __builtin_amdgcn_mfma_f32_16x16x32_bf16(ax, wx[ktx][s], accA[s], 0, 0, 0);
        }
        // h part (bf16x2: (h_hi + h_lo) * W_hi), kt 0..1 -> accA, kt 2..3 -> accB
#pragma unroll
        for (int kth = 0; kth < 2; ++kth) {
            uint ra = (rowbase + 128u + (uint)kth * 64 + g16) ^ rswz;
            short8 ah = *(const short8*)(ph + ra);
            short8 al = *(const short8*)(pl + ra);
#pragma unroll
            for (int s = 0; s < 4; ++s)
                accA[s] = __builtin_amdgcn_mfma_f32_16x16x32_bf16(ah, wh[kth][s], accA[s], 0, 0, 0);
#pragma unroll
            for (int s = 0; s < 4; ++s)
                accA[s] = __builtin_amdgcn_mfma_f32_16x16x32_bf16(al, wh[kth][s], accA[s], 0, 0, 0);
        }
#pragma unroll
        for (int kth = 2; kth < 4; ++kth) {
            uint ra = (rowbase + 128u + (uint)kth * 64 + g16) ^ rswz;
            short8 ah = *(const short8*)(ph + ra);
            short8 al = *(const short8*)(pl + ra);
#pragma unroll
            for (int s = 0; s < 4; ++s)
                accB[s] = __builtin_amdgcn_mfma_f32_16x16x32_bf16(ah, wh[kth][s], accB[s], 0, 0, 0);
#pragma unroll
            for (int s = 0; s < 4; ++s)
                accB[s] = __builtin_amdgcn_mfma_f32_16x16x32_bf16(al, wh[kth][s], accB[s], 0, 0, 0);
        }

        // pointwise LSTM cell (lane-local)
#pragma unroll
        for (int r = 0; r < 4; ++r) {
            float gi = sigf(accA[0][r] + accB[0][r]);
            float gf = sigf(accA[1][r] + accB[1][r]);
            float gg = tanhf_fast(accA[2][r] + accB[2][r]);
            float go = sigf(accA[3][r] + accB[3][r]);
            cst[r] = gf * cst[r] + gi * gg;
            hreg[r] = go * tanhf_fast(cst[r]);
        }

        if (t < T_STEPS - 1) {
            // stage h(t) hi/lo into next buffer
#pragma unroll
            for (int r = 0; r < 4; ++r) {
                float hv = hreg[r];
                ushort hh = f2bf(hv);
                *(ushort*)(qh + hwa[r]) = hh;
                *(ushort*)(ql + hwa[r]) = f2bf(hv - bf2f(hh));
            }
            __syncthreads();
        }
    }

#pragma unroll
    for (int r = 0; r < 4; ++r)
        hfin[(size_t)(b0 + hrow0 + r) * 128 + jl] = hreg[r];
}

// ---------------------------------------------------------------------------
// post: per row: u=tanh(W1c@h); v=W2@u; res=W0@h+127v; LN; linear; tile 196x.
// ---------------------------------------------------------------------------
__global__ __launch_bounds__(128) void post_kernel(const char* __restrict__ wsb,
                                                   const float* __restrict__ ln_g,
                                                   const float* __restrict__ ln_b,
                                                   const float* __restrict__ lin_b,
                                                   float* __restrict__ out) {
    const float* hfinal = (const float*)(wsb + OFF_HFIN);
    const float* W1cT   = (const float*)(wsb + OFF_W1CT);
    const float* W2T    = (const float*)(wsb + OFF_W2T);
    const float* W0T    = (const float*)(wsb + OFF_W0T);
    const float* linWT  = (const float*)(wsb + OFF_LINWT);

    __shared__ float sh[128], su[128], sres[128], spart[4];
    int b = blockIdx.x, f = threadIdx.x;

    sh[f] = hfinal[(size_t)b * 128 + f];
    __syncthreads();

    float acc = 0.f;
#pragma unroll 4
    for (int k = 0; k < 128; ++k) acc += W1cT[k * 128 + f] * sh[k];
    su[f] = tanhf_fast(acc);
    __syncthreads();

    float v = 0.f, r0 = 0.f;
#pragma unroll 4
    for (int k = 0; k < 128; ++k) {
        v  += W2T[k * 128 + f] * su[k];
        r0 += W0T[k * 128 + f] * sh[k];
    }
    float res = r0 + 127.f * v;

    int lane = f & 63, wid = f >> 6;
    float s = res;
#pragma unroll
    for (int off = 32; off > 0; off >>= 1) s += __shfl_down(s, off);
    if (lane == 0) spart[wid] = s;
    __syncthreads();
    float mu = (spart[0] + spart[1]) * (1.f / 128.f);
    float d = res - mu;
    float s2 = d * d;
#pragma unroll
    for (int off = 32; off > 0; off >>= 1) s2 += __shfl_down(s2, off);
    if (lane == 0) spart[2 + wid] = s2;
    __syncthreads();
    float var = (spart[2] + spart[3]) * (1.f / 128.f);
    float rn = d * rsqrtf(var + 1e-5f) * ln_g[f] + ln_b[f];
    sres[f] = rn;
    __syncthreads();

    float o = lin_b[f];
#pragma unroll 4
    for (int k = 0; k < 128; ++k) o += linWT[k * 128 + f] * sres[k];

    float* op = out + (size_t)b * 196 * 128 + f;
#pragma unroll 4
    for (int i = 0; i < 196; ++i) op[i * 128] = o;
}

// ---------------------------------------------------------------------------
extern "C" void kernel_launch(void* const* d_in, const int* in_sizes, int n_in,
                              void* d_out, int out_size, void* d_ws, size_t ws_size,
                              hipStream_t stream) {
    const float* x      = (const float*)d_in[0];
    const float* conv_w = (const float*)d_in[1];
    const float* conv_b = (const float*)d_in[2];
    const float* w_ih   = (const float*)d_in[3];
    const float* w_hh   = (const float*)d_in[4];
    const float* b_ih   = (const float*)d_in[5];
    const float* b_hh   = (const float*)d_in[6];
    const float* W1     = (const float*)d_in[7];
    const float* W2     = (const float*)d_in[8];
    const float* W0     = (const float*)d_in[9];
    const float* ln_g   = (const float*)d_in[10];
    const float* ln_b   = (const float*)d_in[11];
    const float* lin_w  = (const float*)d_in[12];
    const float* lin_b  = (const float*)d_in[13];
    char* wsb  = (char*)d_ws;
    float* out = (float*)d_out;

    prep_kernel<<<dim3(321), dim3(512), 0, stream>>>(w_ih, w_hh, b_ih, b_hh,
                                                     W1, W2, W0, lin_w, wsb);
    conv_kernel<<<dim3(1024), dim3(256), 0, stream>>>(x, conv_w, conv_b, wsb);
    lstm_mfma<<<dim3(64), dim3(512), 0, stream>>>(wsb, wsb);
    post_kernel<<<dim3(1024), dim3(128), 0, stream>>>(wsb, ln_g, ln_b, lin_b, out);
}

// Round 8
// 165.575 us; speedup vs baseline: 2.1797x; 1.1710x over previous
//
#include <hip/hip_runtime.h>
#include <math.h>

// ---------------------------------------------------------------------------
// B=1024, conv1d(3->64,k=5,pad=2) T=100, LSTM(64->128) 100 steps (MFMA f16),
// per-row epilogue (W1c tanh, W2, W0, LN, linear), tile to (14,14).
//
// LSTM: 64 blocks x 512 thr (8 waves, 2/SIMD). Block owns 16 batch rows.
// Wave w owns gate-cols [16w,16w+16), 4 gates as 4 acc tiles -> pointwise is
// lane-local. Precision: FULL f16 datapath (weights, x, h all f16, 2^-11 rel;
// c and accumulators fp32). f16 replaces r7's bf16-hi+lo h split: 24 MFMA
// /wave/step (was 40), 6 ds_read_b128 (was 10), 4 h-writes (was 8).
// Error budget: dh~2.4e-4/step -> ~7e-4 accumulated -> ~2e-3 at output after
// 127x epilogue amplification + LN; threshold 0.04.
// ---------------------------------------------------------------------------

#define T_STEPS 100
#define LROW    208          // f16 elems per LDS row (416 B, 16B-aligned)
#define PLANE   (16 * LROW)  // f16 elems per [16][LROW] plane

// workspace byte offsets
#define OFF_WHI    0u          // 98304 f16 = 196608 B
#define OFF_BIAS   393216u     // 512 f32
#define OFF_W1CT   395264u     // 16384 f32
#define OFF_W2T    460800u
#define OFF_W0T    526336u
#define OFF_LINWT  591872u
#define OFF_XHI    657408u     // 100*1024*64 f16
#define OFF_HFIN   26871808u   // 1024*128 f32
// ws total needed: 27396096 B

typedef __attribute__((ext_vector_type(8))) _Float16 half8;
typedef __attribute__((ext_vector_type(4))) float f32x4;

__device__ __forceinline__ float frcp(float x) { return __builtin_amdgcn_rcpf(x); }
__device__ __forceinline__ float sigf(float x) { return frcp(1.f + __expf(-x)); }
__device__ __forceinline__ float tanhf_fast(float x) { return 2.f * frcp(1.f + __expf(-2.f * x)) - 1.f; }

// ---------------------------------------------------------------------------
// prep: pack LSTM weight B-fragments (f16) + bias + epilogue transposes.
// whi[((w*6+kt)*4+s)*512 + l*8 + e] = f16( W_cat[g=s*128+16w+(l&15)][k] ),
//   k = kt*32 + (l>>4)*8 + e
// ---------------------------------------------------------------------------
__global__ void prep_kernel(const float* __restrict__ w_ih, const float* __restrict__ w_hh,
                            const float* __restrict__ b_ih, const float* __restrict__ b_hh,
                            const float* __restrict__ W1, const float* __restrict__ W2,
                            const float* __restrict__ W0, const float* __restrict__ lin_w,
                            char* __restrict__ wsb) {
    _Float16* whi  = (_Float16*)(wsb + OFF_WHI);
    float*  biasv = (float*)(wsb + OFF_BIAS);
    float*  W1cT  = (float*)(wsb + OFF_W1CT);
    float*  W2T   = (float*)(wsb + OFF_W2T);
    float*  W0T   = (float*)(wsb + OFF_W0T);
    float*  linWT = (float*)(wsb + OFF_LINWT);

    int blk = blockIdx.x, tid = threadIdx.x;
    if (blk < 192) {
        int idx = blk * 512 + tid;
        int e = idx & 7;
        int l = (idx >> 3) & 63;
        int s = (idx >> 9) & 3;
        int rem = idx >> 11;           // w*6 + kt
        int kt = rem % 6, w = rem / 6;
        int g = s * 128 + 16 * w + (l & 15);
        int k = kt * 32 + (l >> 4) * 8 + e;
        float v = (k < 64) ? w_ih[g * 64 + k] : w_hh[g * 128 + (k - 64)];
        whi[idx] = (_Float16)v;
    } else if (blk == 192) {
        biasv[tid] = b_ih[tid] + b_hh[tid];
    } else if (blk < 225) {
        int idx = (blk - 193) * 512 + tid;
        int f = idx >> 7, hh = idx & 127;
        W1cT[f * 128 + hh] = W1[hh * 256 + f] + W1[hh * 256 + 128 + f];
    } else if (blk < 257) {
        int idx = (blk - 225) * 512 + tid;
        int h = idx >> 7, f = idx & 127;
        W2T[h * 128 + f] = W2[f * 128 + h];
    } else if (blk < 289) {
        int idx = (blk - 257) * 512 + tid;
        int k = idx >> 7, f = idx & 127;
        W0T[k * 128 + f] = W0[f * 128 + k];
    } else {
        int idx = (blk - 289) * 512 + tid;
        int k = idx >> 7, f = idx & 127;
        linWT[k * 128 + f] = lin_w[f * 128 + k];
    }
}

// ---------------------------------------------------------------------------
// conv: agent = x[:,0] (B,3,100) -> relu(conv1d+b) -> xhi[t][b][k] f16
// ---------------------------------------------------------------------------
__global__ __launch_bounds__(256) void conv_kernel(const float* __restrict__ x,
                                                   const float* __restrict__ conv_w,
                                                   const float* __restrict__ conv_b,
                                                   char* __restrict__ wsb) {
    _Float16* xhi = (_Float16*)(wsb + OFF_XHI);
    __shared__ float sx[3][104];
    __shared__ float sw[960];
    __shared__ float sb[64];
    int b = blockIdx.x, tid = threadIdx.x;

    for (int i = tid; i < 312; i += 256) {
        int c = i / 104, tp = i % 104;
        int t = tp - 2;
        sx[c][tp] = (t >= 0 && t < 100) ? x[b * 38400 + c * 100 + t] : 0.f;
    }
    for (int i = tid; i < 960; i += 256) sw[i] = conv_w[i];
    if (tid < 64) sb[tid] = conv_b[tid];
    __syncthreads();

    for (int i = tid; i < 6400; i += 256) {
        int t = i >> 6, k = i & 63;
        float a = sb[k];
#pragma unroll
        for (int c = 0; c < 3; ++c)
#pragma unroll
            for (int kk = 0; kk < 5; ++kk)
                a += sx[c][t + kk] * sw[k * 15 + c * 5 + kk];
        a = fmaxf(a, 0.f);
        xhi[t * 65536 + b * 64 + k] = (_Float16)a;
    }
}

// ---------------------------------------------------------------------------
// lstm_mfma: 64 blocks x 512 threads, f16 datapath, 1 barrier/step.
// ---------------------------------------------------------------------------
__global__ __launch_bounds__(512, 2)
void lstm_mfma(const char* __restrict__ wsro, char* __restrict__ wsb) {
    const _Float16* whi  = (const _Float16*)(wsro + OFF_WHI);
    const float*  biasv  = (const float*)(wsro + OFF_BIAS);
    const _Float16* xhi  = (const _Float16*)(wsro + OFF_XHI);
    float* hfin = (float*)(wsb + OFF_HFIN);

    __shared__ _Float16 L[2][16][LROW];   // [buf][row][col] (x: 0..63, h: 64..191)

    int tid = threadIdx.x;
    int w = tid >> 6, l = tid & 63;
    int b0 = blockIdx.x * 16;

    // ---- weights pinned in regs: x-part (8 frags), h-part (16 frags) = 96 regs
    half8 wx[2][4];                   // kt 0..1 (K 0..63)
    half8 wh[4][4];                   // kt 2..5 (K 64..191)
#pragma unroll
    for (int ktx = 0; ktx < 2; ++ktx)
#pragma unroll
        for (int s = 0; s < 4; ++s)
            wx[ktx][s] = *(const half8*)(whi + (((w * 6 + ktx) * 4 + s) * 64 + l) * 8);
#pragma unroll
    for (int kth = 0; kth < 4; ++kth)
#pragma unroll
        for (int s = 0; s < 4; ++s)
            wh[kth][s] = *(const half8*)(whi + (((w * 6 + 2 + kth) * 4 + s) * 64 + l) * 8);

    int jl = 16 * w + (l & 15);
    float bv[4];
#pragma unroll
    for (int s = 0; s < 4; ++s) bv[s] = biasv[s * 128 + jl];

    int arow = l & 15;
    int g16  = (l >> 4) * 16;
    uint rowbase = (uint)arow * (LROW * 2);
    uint rswz    = (uint)(arow & 7) << 4;
    int hrow0 = (l >> 4) * 4;

    // x staging address (byte offset within a plane), swizzled
    int xr = tid >> 5;
    uint xw = ((uint)xr * (LROW * 2) + (uint)(tid & 31) * 4) ^ ((uint)(xr & 7) << 4);

    // h write offsets for r=0..3 (byte offsets)
    uint hwa[4];
#pragma unroll
    for (int r = 0; r < 4; ++r) {
        uint row = (uint)(hrow0 + r);
        hwa[r] = (row * (LROW * 2) + 128u + 2u * (uint)jl) ^ ((row & 7u) << 4);
    }

    float cst[4]  = {0.f, 0.f, 0.f, 0.f};
    float hreg[4] = {0.f, 0.f, 0.f, 0.f};

    // zero LDS (h regions must read 0 at t=0)
    for (int i = tid; i < 2 * PLANE; i += 512) ((_Float16*)L)[i] = (_Float16)0.f;

    // prologue: x(0) staged into buf0, vx holds x(1)
    size_t xoff0 = (size_t)b0 * 64 + (size_t)tid * 2;
    uint vx = *(const uint*)(xhi + xoff0);
    __syncthreads();                       // zeros visible
    *(uint*)((char*)&L[0][0][0] + xw) = vx;
    vx = *(const uint*)(xhi + xoff0 + 65536);
    __syncthreads();                       // x(0) visible

    for (int t = 0; t < T_STEPS; ++t) {
        int p = t & 1;
        const char* ph = (const char*)&L[p][0][0];
        char* qh = (char*)&L[p ^ 1][0][0];

        // TOP of step: stage x(t+1) from regs; issue prefetch x(t+2) so it
        // has the whole step before the barrier's vmcnt drain.
        if (t < T_STEPS - 1) {
            *(uint*)(qh + xw) = vx;
            int tn = (t + 2 < T_STEPS) ? t + 2 : T_STEPS - 1;
            vx = *(const uint*)(xhi + xoff0 + (size_t)tn * 65536);
        }

        f32x4 accA[4], accB[4];
#pragma unroll
        for (int s = 0; s < 4; ++s) {
            accA[s] = (f32x4){bv[s], bv[s], bv[s], bv[s]};
            accB[s] = (f32x4){0.f, 0.f, 0.f, 0.f};
        }

        // x part -> accA   [chain depth 2]
#pragma unroll
        for (int ktx = 0; ktx < 2; ++ktx) {
            half8 ax = *(const half8*)(ph + ((rowbase + (uint)ktx * 64 + g16) ^ rswz));
#pragma unroll
            for (int s = 0; s < 4; ++s)
                accA[s] = __builtin_amdgcn_mfma_f32_16x16x32_f16(ax, wx[ktx][s], accA[s], 0, 0, 0);
        }
        // h part: kt 0..1 -> accA (depth +2), kt 2..3 -> accB (depth 2)
#pragma unroll
        for (int kth = 0; kth < 2; ++kth) {
            half8 ah = *(const half8*)(ph + ((rowbase + 128u + (uint)kth * 64 + g16) ^ rswz));
#pragma unroll
            for (int s = 0; s < 4; ++s)
                accA[s] = __builtin_amdgcn_mfma_f32_16x16x32_f16(ah, wh[kth][s], accA[s], 0, 0, 0);
        }
#pragma unroll
        for (int kth = 2; kth < 4; ++kth) {
            half8 ah = *(const half8*)(ph + ((rowbase + 128u + (uint)kth * 64 + g16) ^ rswz));
#pragma unroll
            for (int s = 0; s < 4; ++s)
                accB[s] = __builtin_amdgcn_mfma_f32_16x16x32_f16(ah, wh[kth][s], accB[s], 0, 0, 0);
        }

        // pointwise LSTM cell (lane-local)
#pragma unroll
        for (int r = 0; r < 4; ++r) {
            float gi = sigf(accA[0][r] + accB[0][r]);
            float gf = sigf(accA[1][r] + accB[1][r]);
            float gg = tanhf_fast(accA[2][r] + accB[2][r]);
            float go = sigf(accA[3][r] + accB[3][r]);
            cst[r] = gf * cst[r] + gi * gg;
            hreg[r] = go * tanhf_fast(cst[r]);
        }

        if (t < T_STEPS - 1) {
            // stage h(t) (f16, single plane) into next buffer
#pragma unroll
            for (int r = 0; r < 4; ++r)
                *(_Float16*)(qh + hwa[r]) = (_Float16)hreg[r];
            __syncthreads();
        }
    }

#pragma unroll
    for (int r = 0; r < 4; ++r)
        hfin[(size_t)(b0 + hrow0 + r) * 128 + jl] = hreg[r];
}

// ---------------------------------------------------------------------------
// post: per row: u=tanh(W1c@h); v=W2@u; res=W0@h+127v; LN; linear; tile 196x.
// ---------------------------------------------------------------------------
__global__ __launch_bounds__(128) void post_kernel(const char* __restrict__ wsb,
                                                   const float* __restrict__ ln_g,
                                                   const float* __restrict__ ln_b,
                                                   const float* __restrict__ lin_b,
                                                   float* __restrict__ out) {
    const float* hfinal = (const float*)(wsb + OFF_HFIN);
    const float* W1cT   = (const float*)(wsb + OFF_W1CT);
    const float* W2T    = (const float*)(wsb + OFF_W2T);
    const float* W0T    = (const float*)(wsb + OFF_W0T);
    const float* linWT  = (const float*)(wsb + OFF_LINWT);

    __shared__ float sh[128], su[128], sres[128], spart[4];
    int b = blockIdx.x, f = threadIdx.x;

    sh[f] = hfinal[(size_t)b * 128 + f];
    __syncthreads();

    float acc = 0.f;
#pragma unroll 4
    for (int k = 0; k < 128; ++k) acc += W1cT[k * 128 + f] * sh[k];
    su[f] = tanhf_fast(acc);
    __syncthreads();

    float v = 0.f, r0 = 0.f;
#pragma unroll 4
    for (int k = 0; k < 128; ++k) {
        v  += W2T[k * 128 + f] * su[k];
        r0 += W0T[k * 128 + f] * sh[k];
    }
    float res = r0 + 127.f * v;

    int lane = f & 63, wid = f >> 6;
    float s = res;
#pragma unroll
    for (int off = 32; off > 0; off >>= 1) s += __shfl_down(s, off);
    if (lane == 0) spart[wid] = s;
    __syncthreads();
    float mu = (spart[0] + spart[1]) * (1.f / 128.f);
    float d = res - mu;
    float s2 = d * d;
#pragma unroll
    for (int off = 32; off > 0; off >>= 1) s2 += __shfl_down(s2, off);
    if (lane == 0) spart[2 + wid] = s2;
    __syncthreads();
    float var = (spart[2] + spart[3]) * (1.f / 128.f);
    float rn = d * rsqrtf(var + 1e-5f) * ln_g[f] + ln_b[f];
    sres[f] = rn;
    __syncthreads();

    float o = lin_b[f];
#pragma unroll 4
    for (int k = 0; k < 128; ++k) o += linWT[k * 128 + f] * sres[k];

    float* op = out + (size_t)b * 196 * 128 + f;
#pragma unroll 4
    for (int i = 0; i < 196; ++i) op[i * 128] = o;
}

// ---------------------------------------------------------------------------
extern "C" void kernel_launch(void* const* d_in, const int* in_sizes, int n_in,
                              void* d_out, int out_size, void* d_ws, size_t ws_size,
                              hipStream_t stream) {
    const float* x      = (const float*)d_in[0];
    const float* conv_w = (const float*)d_in[1];
    const float* conv_b = (const float*)d_in[2];
    const float* w_ih   = (const float*)d_in[3];
    const float* w_hh   = (const float*)d_in[4];
    const float* b_ih   = (const float*)d_in[5];
    const float* b_hh   = (const float*)d_in[6];
    const float* W1     = (const float*)d_in[7];
    const float* W2     = (const float*)d_in[8];
    const float* W0     = (const float*)d_in[9];
    const float* ln_g   = (const float*)d_in[10];
    const float* ln_b   = (const float*)d_in[11];
    const float* lin_w  = (const float*)d_in[12];
    const float* lin_b  = (const float*)d_in[13];
    char* wsb  = (char*)d_ws;
    float* out = (float*)d_out;

    prep_kernel<<<dim3(321), dim3(512), 0, stream>>>(w_ih, w_hh, b_ih, b_hh,
                                                     W1, W2, W0, lin_w, wsb);
    conv_kernel<<<dim3(1024), dim3(256), 0, stream>>>(x, conv_w, conv_b, wsb);
    lstm_mfma<<<dim3(64), dim3(512), 0, stream>>>(wsb, wsb);
    post_kernel<<<dim3(1024), dim3(128), 0, stream>>>(wsb, ln_g, ln_b, lin_b, out);
}

// Round 10
// 159.655 us; speedup vs baseline: 2.2606x; 1.0371x over previous
//
#include <hip/hip_runtime.h>
#include <math.h>

// ---------------------------------------------------------------------------
// B=1024, conv1d(3->64,k=5,pad=2) T=100, LSTM(64->128) 100 steps (MFMA f16),
// per-row epilogue (W1c tanh, W2, W0, LN, linear), tile to (14,14).
//
// LSTM: 64 blocks x 512 thr (8 waves, 2/SIMD). Block owns 16 batch rows.
// r10 = r8 (known-pass, lstm 104.5us) + ONLY two non-structural deltas:
//  (1) exp2-folded weights/bias: W' = -log2e*W (i,f,o), -2log2e*W (g).
//      Pointwise = v_exp (builtin exp2f) + rcp, zero pre-exp muls.
//  (2) post_kernel float4 tiled store.
// r9's big-bang rewrite (resident-x LDS + new layouts + asm exp) failed
// correctness (absmax 3.6); bisecting from the r8 base isolates the folding.
// ---------------------------------------------------------------------------

#define T_STEPS 100
#define LROW    208          // f16 elems per LDS row (416 B, 16B-aligned)
#define PLANE   (16 * LROW)  // f16 elems per [16][LROW] plane

// workspace byte offsets
#define OFF_WHI    0u          // 98304 f16 folded weights
#define OFF_BIAS   393216u     // 512 f32 folded bias
#define OFF_W1CT   395264u     // 16384 f32
#define OFF_W2T    460800u
#define OFF_W0T    526336u
#define OFF_LINWT  591872u
#define OFF_XHI    657408u     // 100*1024*64 f16
#define OFF_HFIN   26871808u   // 1024*128 f32

typedef __attribute__((ext_vector_type(8))) _Float16 half8;
typedef __attribute__((ext_vector_type(4))) float f32x4;

__device__ __forceinline__ float frcp(float x) { return __builtin_amdgcn_rcpf(x); }
__device__ __forceinline__ float fexp2(float x) { return __builtin_amdgcn_exp2f(x); }
__device__ __forceinline__ float tanhf_fast(float x) { return 2.f * frcp(1.f + __expf(-2.f * x)) - 1.f; }

// ---------------------------------------------------------------------------
// prep: pack FOLDED LSTM weight B-fragments (f16) + folded bias + epilogue
// transposes. fold[s] = -log2e (i,f,o), -2log2e (g) => pointwise is raw 2^x.
// ---------------------------------------------------------------------------
__global__ void prep_kernel(const float* __restrict__ w_ih, const float* __restrict__ w_hh,
                            const float* __restrict__ b_ih, const float* __restrict__ b_hh,
                            const float* __restrict__ W1, const float* __restrict__ W2,
                            const float* __restrict__ W0, const float* __restrict__ lin_w,
                            char* __restrict__ wsb) {
    _Float16* whi  = (_Float16*)(wsb + OFF_WHI);
    float*  biasv = (float*)(wsb + OFF_BIAS);
    float*  W1cT  = (float*)(wsb + OFF_W1CT);
    float*  W2T   = (float*)(wsb + OFF_W2T);
    float*  W0T   = (float*)(wsb + OFF_W0T);
    float*  linWT = (float*)(wsb + OFF_LINWT);

    const float fold[4] = {-1.4426950408889634f, -1.4426950408889634f,
                           -2.8853900817779268f, -1.4426950408889634f};

    int blk = blockIdx.x, tid = threadIdx.x;
    if (blk < 192) {
        int idx = blk * 512 + tid;
        int e = idx & 7;
        int l = (idx >> 3) & 63;
        int s = (idx >> 9) & 3;
        int rem = idx >> 11;           // w*6 + kt
        int kt = rem % 6, w = rem / 6;
        int g = s * 128 + 16 * w + (l & 15);
        int k = kt * 32 + (l >> 4) * 8 + e;
        float v = (k < 64) ? w_ih[g * 64 + k] : w_hh[g * 128 + (k - 64)];
        whi[idx] = (_Float16)(v * fold[s]);
    } else if (blk == 192) {
        int s = tid >> 7;
        biasv[tid] = (b_ih[tid] + b_hh[tid]) * fold[s];
    } else if (blk < 225) {
        int idx = (blk - 193) * 512 + tid;
        int f = idx >> 7, hh = idx & 127;
        W1cT[f * 128 + hh] = W1[hh * 256 + f] + W1[hh * 256 + 128 + f];
    } else if (blk < 257) {
        int idx = (blk - 225) * 512 + tid;
        int h = idx >> 7, f = idx & 127;
        W2T[h * 128 + f] = W2[f * 128 + h];
    } else if (blk < 289) {
        int idx = (blk - 257) * 512 + tid;
        int k = idx >> 7, f = idx & 127;
        W0T[k * 128 + f] = W0[f * 128 + k];
    } else {
        int idx = (blk - 289) * 512 + tid;
        int k = idx >> 7, f = idx & 127;
        linWT[k * 128 + f] = lin_w[f * 128 + k];
    }
}

// ---------------------------------------------------------------------------
// conv: agent = x[:,0] (B,3,100) -> relu(conv1d+b) -> xhi[t][b][k] f16
// ---------------------------------------------------------------------------
__global__ __launch_bounds__(256) void conv_kernel(const float* __restrict__ x,
                                                   const float* __restrict__ conv_w,
                                                   const float* __restrict__ conv_b,
                                                   char* __restrict__ wsb) {
    _Float16* xhi = (_Float16*)(wsb + OFF_XHI);
    __shared__ float sx[3][104];
    __shared__ float sw[960];
    __shared__ float sb[64];
    int b = blockIdx.x, tid = threadIdx.x;

    for (int i = tid; i < 312; i += 256) {
        int c = i / 104, tp = i % 104;
        int t = tp - 2;
        sx[c][tp] = (t >= 0 && t < 100) ? x[b * 38400 + c * 100 + t] : 0.f;
    }
    for (int i = tid; i < 960; i += 256) sw[i] = conv_w[i];
    if (tid < 64) sb[tid] = conv_b[tid];
    __syncthreads();

    for (int i = tid; i < 6400; i += 256) {
        int t = i >> 6, k = i & 63;
        float a = sb[k];
#pragma unroll
        for (int c = 0; c < 3; ++c)
#pragma unroll
            for (int kk = 0; kk < 5; ++kk)
                a += sx[c][t + kk] * sw[k * 15 + c * 5 + kk];
        a = fmaxf(a, 0.f);
        xhi[t * 65536 + b * 64 + k] = (_Float16)a;
    }
}

// ---------------------------------------------------------------------------
// lstm_mfma: 64 blocks x 512 threads, f16 datapath, 1 barrier/step.
// (structure identical to round 8)
// ---------------------------------------------------------------------------
__global__ __launch_bounds__(512, 2)
void lstm_mfma(const char* __restrict__ wsro, char* __restrict__ wsb) {
    const _Float16* whi  = (const _Float16*)(wsro + OFF_WHI);
    const float*  biasv  = (const float*)(wsro + OFF_BIAS);
    const _Float16* xhi  = (const _Float16*)(wsro + OFF_XHI);
    float* hfin = (float*)(wsb + OFF_HFIN);

    __shared__ _Float16 L[2][16][LROW];   // [buf][row][col] (x: 0..63, h: 64..191)

    int tid = threadIdx.x;
    int w = tid >> 6, l = tid & 63;
    int b0 = blockIdx.x * 16;

    // ---- folded weights pinned in regs: x-part 8 frags, h-part 16 frags
    half8 wx[2][4];                   // kt 0..1 (K 0..63)
    half8 wh[4][4];                   // kt 2..5 (K 64..191)
#pragma unroll
    for (int ktx = 0; ktx < 2; ++ktx)
#pragma unroll
        for (int s = 0; s < 4; ++s)
            wx[ktx][s] = *(const half8*)(whi + (((w * 6 + ktx) * 4 + s) * 64 + l) * 8);
#pragma unroll
    for (int kth = 0; kth < 4; ++kth)
#pragma unroll
        for (int s = 0; s < 4; ++s)
            wh[kth][s] = *(const half8*)(whi + (((w * 6 + 2 + kth) * 4 + s) * 64 + l) * 8);

    int jl = 16 * w + (l & 15);
    float bv[4];
#pragma unroll
    for (int s = 0; s < 4; ++s) bv[s] = biasv[s * 128 + jl];

    int arow = l & 15;
    int g16  = (l >> 4) * 16;
    uint rowbase = (uint)arow * (LROW * 2);
    uint rswz    = (uint)(arow & 7) << 4;
    int hrow0 = (l >> 4) * 4;

    // x staging address (byte offset within a plane), swizzled
    int xr = tid >> 5;
    uint xw = ((uint)xr * (LROW * 2) + (uint)(tid & 31) * 4) ^ ((uint)(xr & 7) << 4);

    // h write offsets for r=0..3 (byte offsets)
    uint hwa[4];
#pragma unroll
    for (int r = 0; r < 4; ++r) {
        uint row = (uint)(hrow0 + r);
        hwa[r] = (row * (LROW * 2) + 128u + 2u * (uint)jl) ^ ((row & 7u) << 4);
    }

    float cst[4]  = {0.f, 0.f, 0.f, 0.f};
    float hreg[4] = {0.f, 0.f, 0.f, 0.f};

    // zero LDS (h regions must read 0 at t=0)
    for (int i = tid; i < 2 * PLANE; i += 512) ((_Float16*)L)[i] = (_Float16)0.f;

    // prologue: x(0) staged into buf0, vx holds x(1)
    size_t xoff0 = (size_t)b0 * 64 + (size_t)tid * 2;
    uint vx = *(const uint*)(xhi + xoff0);
    __syncthreads();                       // zeros visible
    *(uint*)((char*)&L[0][0][0] + xw) = vx;
    vx = *(const uint*)(xhi + xoff0 + 65536);
    __syncthreads();                       // x(0) visible

    for (int t = 0; t < T_STEPS; ++t) {
        int p = t & 1;
        const char* ph = (const char*)&L[p][0][0];
        char* qh = (char*)&L[p ^ 1][0][0];

        // TOP of step: stage x(t+1) from regs; issue prefetch x(t+2) so it
        // has the whole step before the barrier's vmcnt drain.
        if (t < T_STEPS - 1) {
            *(uint*)(qh + xw) = vx;
            int tn = (t + 2 < T_STEPS) ? t + 2 : T_STEPS - 1;
            vx = *(const uint*)(xhi + xoff0 + (size_t)tn * 65536);
        }

        f32x4 accA[4], accB[4];
#pragma unroll
        for (int s = 0; s < 4; ++s) {
            accA[s] = (f32x4){bv[s], bv[s], bv[s], bv[s]};
            accB[s] = (f32x4){0.f, 0.f, 0.f, 0.f};
        }

        // x part -> accA   [chain depth 2]
#pragma unroll
        for (int ktx = 0; ktx < 2; ++ktx) {
            half8 ax = *(const half8*)(ph + ((rowbase + (uint)ktx * 64 + g16) ^ rswz));
#pragma unroll
            for (int s = 0; s < 4; ++s)
                accA[s] = __builtin_amdgcn_mfma_f32_16x16x32_f16(ax, wx[ktx][s], accA[s], 0, 0, 0);
        }
        // h part: kt 0..1 -> accA (depth +2), kt 2..3 -> accB (depth 2)
#pragma unroll
        for (int kth = 0; kth < 2; ++kth) {
            half8 ah = *(const half8*)(ph + ((rowbase + 128u + (uint)kth * 64 + g16) ^ rswz));
#pragma unroll
            for (int s = 0; s < 4; ++s)
                accA[s] = __builtin_amdgcn_mfma_f32_16x16x32_f16(ah, wh[kth][s], accA[s], 0, 0, 0);
        }
#pragma unroll
        for (int kth = 2; kth < 4; ++kth) {
            half8 ah = *(const half8*)(ph + ((rowbase + 128u + (uint)kth * 64 + g16) ^ rswz));
#pragma unroll
            for (int s = 0; s < 4; ++s)
                accB[s] = __builtin_amdgcn_mfma_f32_16x16x32_f16(ah, wh[kth][s], accB[s], 0, 0, 0);
        }

        // pointwise LSTM cell (lane-local), exp2-folded: acc = -log2e*z
        // (i,f,o) or -2log2e*z (g); sigmoid = rcp(1+2^acc), tanh = 2*rcp-1.
#pragma unroll
        for (int r = 0; r < 4; ++r) {
            float Ei = fexp2(accA[0][r] + accB[0][r]);
            float Ef = fexp2(accA[1][r] + accB[1][r]);
            float Eg = fexp2(accA[2][r] + accB[2][r]);
            float Eo = fexp2(accA[3][r] + accB[3][r]);
            float si = frcp(1.f + Ei);
            float sf = frcp(1.f + Ef);
            float tg = 2.f * frcp(1.f + Eg) - 1.f;
            float so = frcp(1.f + Eo);
            cst[r] = sf * cst[r] + si * tg;
            float tc = 2.f * frcp(1.f + fexp2(cst[r] * -2.8853900817779268f)) - 1.f;
            hreg[r] = so * tc;
        }

        if (t < T_STEPS - 1) {
            // stage h(t) (f16, single plane) into next buffer
#pragma unroll
            for (int r = 0; r < 4; ++r)
                *(_Float16*)(qh + hwa[r]) = (_Float16)hreg[r];
            __syncthreads();
        }
    }

#pragma unroll
    for (int r = 0; r < 4; ++r)
        hfin[(size_t)(b0 + hrow0 + r) * 128 + jl] = hreg[r];
}

// ---------------------------------------------------------------------------
// post: per row: u=tanh(W1c@h); v=W2@u; res=W0@h+127v; LN; linear; tile 196x
// with float4 stores.
// ---------------------------------------------------------------------------
__global__ __launch_bounds__(128) void post_kernel(const char* __restrict__ wsb,
                                                   const float* __restrict__ ln_g,
                                                   const float* __restrict__ ln_b,
                                                   const float* __restrict__ lin_b,
                                                   float* __restrict__ out) {
    const float* hfinal = (const float*)(wsb + OFF_HFIN);
    const float* W1cT   = (const float*)(wsb + OFF_W1CT);
    const float* W2T    = (const float*)(wsb + OFF_W2T);
    const float* W0T    = (const float*)(wsb + OFF_W0T);
    const float* linWT  = (const float*)(wsb + OFF_LINWT);

    __shared__ float sh[128], su[128], sres[128], so_[128], spart[4];
    int b = blockIdx.x, f = threadIdx.x;

    sh[f] = hfinal[(size_t)b * 128 + f];
    __syncthreads();

    float acc = 0.f;
#pragma unroll 4
    for (int k = 0; k < 128; ++k) acc += W1cT[k * 128 + f] * sh[k];
    su[f] = tanhf_fast(acc);
    __syncthreads();

    float v = 0.f, r0 = 0.f;
#pragma unroll 4
    for (int k = 0; k < 128; ++k) {
        v  += W2T[k * 128 + f] * su[k];
        r0 += W0T[k * 128 + f] * sh[k];
    }
    float res = r0 + 127.f * v;

    int lane = f & 63, wid = f >> 6;
    float s = res;
#pragma unroll
    for (int off = 32; off > 0; off >>= 1) s += __shfl_down(s, off);
    if (lane == 0) spart[wid] = s;
    __syncthreads();
    float mu = (spart[0] + spart[1]) * (1.f / 128.f);
    float d = res - mu;
    float s2 = d * d;
#pragma unroll
    for (int off = 32; off > 0; off >>= 1) s2 += __shfl_down(s2, off);
    if (lane == 0) spart[2 + wid] = s2;
    __syncthreads();
    float var = (spart[2] + spart[3]) * (1.f / 128.f);
    float rn = d * rsqrtf(var + 1e-5f) * ln_g[f] + ln_b[f];
    sres[f] = rn;
    __syncthreads();

    float o = lin_b[f];
#pragma unroll 4
    for (int k = 0; k < 128; ++k) o += linWT[k * 128 + f] * sres[k];
    so_[f] = o;
    __syncthreads();

    // tile to (14,14): 196*128 f32 = 6272 float4 per row b
    float4 val = *(const float4*)&so_[(f & 31) << 2];
    float4* op4 = (float4*)(out + (size_t)b * 25088);
#pragma unroll 7
    for (int i = 0; i < 49; ++i) op4[i * 128 + f] = val;
}

// ---------------------------------------------------------------------------
extern "C" void kernel_launch(void* const* d_in, const int* in_sizes, int n_in,
                              void* d_out, int out_size, void* d_ws, size_t ws_size,
                              hipStream_t stream) {
    const float* x      = (const float*)d_in[0];
    const float* conv_w = (const float*)d_in[1];
    const float* conv_b = (const float*)d_in[2];
    const float* w_ih   = (const float*)d_in[3];
    const float* w_hh   = (const float*)d_in[4];
    const float* b_ih   = (const float*)d_in[5];
    const float* b_hh   = (const float*)d_in[6];
    const float* W1     = (const float*)d_in[7];
    const float* W2     = (const float*)d_in[8];
    const float* W0     = (const float*)d_in[9];
    const float* ln_g   = (const float*)d_in[10];
    const float* ln_b   = (const float*)d_in[11];
    const float* lin_w  = (const float*)d_in[12];
    const float* lin_b  = (const float*)d_in[13];
    char* wsb  = (char*)d_ws;
    float* out = (float*)d_out;

    prep_kernel<<<dim3(321), dim3(512), 0, stream>>>(w_ih, w_hh, b_ih, b_hh,
                                                     W1, W2, W0, lin_w, wsb);
    conv_kernel<<<dim3(1024), dim3(256), 0, stream>>>(x, conv_w, conv_b, wsb);
    lstm_mfma<<<dim3(64), dim3(512), 0, stream>>>(wsb, wsb);
    post_kernel<<<dim3(1024), dim3(128), 0, stream>>>(wsb, ln_g, ln_b, lin_b, out);
}

// Round 11
// 148.366 us; speedup vs baseline: 2.4326x; 1.0761x over previous
//
#include <hip/hip_runtime.h>
#include <math.h>

// ---------------------------------------------------------------------------
// B=1024, conv1d(3->64,k=5,pad=2) T=100, LSTM(64->128) 100 steps (MFMA f16),
// per-row epilogue (W1c tanh, W2, W0, LN, linear), tile to (14,14).
//
// LSTM: 64 blocks x 512 thr (8 waves, 2/SIMD). Block owns 16 batch rows.
// r11 = r10 + VALU diet (r10 counters: step 2364cyc = MFMA 931 + VALU 1340,
// no overlap; VALU binds):
//  (1) rcp-merged pointwise: sig(i)*tanh(g) = (1-Eg)*rcp((1+Ei)(1+Eg));
//      sig(o)*tanh(c) = (1-Ec)*rcp((1+Eo)(1+Ec)). 8 trans/elem (was 10).
//  (2) single MFMA acc chain seeded by bias as the C operand (no accB,
//      no init movs, no merge adds).
//  (3) prep+conv fused into one launch.
// Recurrence caps active CUs at 64 (16 rows/block forced by MFMA M=16,
// gate dim must stay in-block); per-CU VALU is the pole.
// ---------------------------------------------------------------------------

#define T_STEPS 100
#define LROW    208          // f16 elems per LDS row (416 B, 16B-aligned)
#define PLANE   (16 * LROW)  // f16 elems per [16][LROW] plane

// workspace byte offsets
#define OFF_WHI    0u          // 98304 f16 folded weights
#define OFF_BIAS   393216u     // 512 f32 folded bias
#define OFF_W1CT   395264u     // 16384 f32
#define OFF_W2T    460800u
#define OFF_W0T    526336u
#define OFF_LINWT  591872u
#define OFF_XHI    657408u     // 100*1024*64 f16
#define OFF_HFIN   26871808u   // 1024*128 f32

typedef __attribute__((ext_vector_type(8))) _Float16 half8;
typedef __attribute__((ext_vector_type(4))) float f32x4;

__device__ __forceinline__ float frcp(float x) { return __builtin_amdgcn_rcpf(x); }
__device__ __forceinline__ float fexp2(float x) { return __builtin_amdgcn_exp2f(x); }
__device__ __forceinline__ float tanhf_fast(float x) { return 2.f * frcp(1.f + __expf(-2.f * x)) - 1.f; }

#define MF16(A, B, C) __builtin_amdgcn_mfma_f32_16x16x32_f16((A), (B), (C), 0, 0, 0)

// ---------------------------------------------------------------------------
// prep_conv: blk<321 = weight packing (folded) + epilogue transposes;
//            blk>=321 = conv for batch row (blk-321).
// fold[s] = -log2e (i,f,o), -2log2e (g) => pointwise is raw 2^x.
// ---------------------------------------------------------------------------
__global__ __launch_bounds__(512)
void prep_conv_kernel(const float* __restrict__ w_ih, const float* __restrict__ w_hh,
                      const float* __restrict__ b_ih, const float* __restrict__ b_hh,
                      const float* __restrict__ W1, const float* __restrict__ W2,
                      const float* __restrict__ W0, const float* __restrict__ lin_w,
                      const float* __restrict__ x, const float* __restrict__ conv_w,
                      const float* __restrict__ conv_b, char* __restrict__ wsb) {
    __shared__ float sx[3][104];
    __shared__ float sw[960];
    __shared__ float sb[64];

    _Float16* whi  = (_Float16*)(wsb + OFF_WHI);
    float*  biasv = (float*)(wsb + OFF_BIAS);
    float*  W1cT  = (float*)(wsb + OFF_W1CT);
    float*  W2T   = (float*)(wsb + OFF_W2T);
    float*  W0T   = (float*)(wsb + OFF_W0T);
    float*  linWT = (float*)(wsb + OFF_LINWT);
    _Float16* xhi = (_Float16*)(wsb + OFF_XHI);

    const float fold[4] = {-1.4426950408889634f, -1.4426950408889634f,
                           -2.8853900817779268f, -1.4426950408889634f};

    int blk = blockIdx.x, tid = threadIdx.x;
    if (blk < 192) {
        int idx = blk * 512 + tid;
        int e = idx & 7;
        int l = (idx >> 3) & 63;
        int s = (idx >> 9) & 3;
        int rem = idx >> 11;           // w*6 + kt
        int kt = rem % 6, w = rem / 6;
        int g = s * 128 + 16 * w + (l & 15);
        int k = kt * 32 + (l >> 4) * 8 + e;
        float v = (k < 64) ? w_ih[g * 64 + k] : w_hh[g * 128 + (k - 64)];
        whi[idx] = (_Float16)(v * fold[s]);
    } else if (blk == 192) {
        int s = tid >> 7;
        biasv[tid] = (b_ih[tid] + b_hh[tid]) * fold[s];
    } else if (blk < 225) {
        int idx = (blk - 193) * 512 + tid;
        int f = idx >> 7, hh = idx & 127;
        W1cT[f * 128 + hh] = W1[hh * 256 + f] + W1[hh * 256 + 128 + f];
    } else if (blk < 257) {
        int idx = (blk - 225) * 512 + tid;
        int h = idx >> 7, f = idx & 127;
        W2T[h * 128 + f] = W2[f * 128 + h];
    } else if (blk < 289) {
        int idx = (blk - 257) * 512 + tid;
        int k = idx >> 7, f = idx & 127;
        W0T[k * 128 + f] = W0[f * 128 + k];
    } else if (blk < 321) {
        int idx = (blk - 289) * 512 + tid;
        int k = idx >> 7, f = idx & 127;
        linWT[k * 128 + f] = lin_w[f * 128 + k];
    } else {
        // conv for batch row b
        int b = blk - 321;
        for (int i = tid; i < 312; i += 512) {
            int c = i / 104, tp = i % 104;
            int t = tp - 2;
            sx[c][tp] = (t >= 0 && t < 100) ? x[b * 38400 + c * 100 + t] : 0.f;
        }
        for (int i = tid; i < 960; i += 512) sw[i] = conv_w[i];
        if (tid < 64) sb[tid] = conv_b[tid];
        __syncthreads();

        for (int i = tid; i < 6400; i += 512) {
            int t = i >> 6, k = i & 63;
            float a = sb[k];
#pragma unroll
            for (int c = 0; c < 3; ++c)
#pragma unroll
                for (int kk = 0; kk < 5; ++kk)
                    a += sx[c][t + kk] * sw[k * 15 + c * 5 + kk];
            a = fmaxf(a, 0.f);
            xhi[t * 65536 + b * 64 + k] = (_Float16)a;
        }
    }
}

// ---------------------------------------------------------------------------
// lstm_mfma: 64 blocks x 512 threads, f16 datapath, 1 barrier/step.
// ---------------------------------------------------------------------------
__global__ __launch_bounds__(512, 2)
void lstm_mfma(const char* __restrict__ wsro, char* __restrict__ wsb) {
    const _Float16* whi  = (const _Float16*)(wsro + OFF_WHI);
    const float*  biasv  = (const float*)(wsro + OFF_BIAS);
    const _Float16* xhi  = (const _Float16*)(wsro + OFF_XHI);
    float* hfin = (float*)(wsb + OFF_HFIN);

    __shared__ _Float16 L[2][16][LROW];   // [buf][row][col] (x: 0..63, h: 64..191)

    int tid = threadIdx.x;
    int w = tid >> 6, l = tid & 63;
    int b0 = blockIdx.x * 16;

    // ---- folded weights pinned in regs: x-part 8 frags, h-part 16 frags
    half8 wx[2][4];                   // kt 0..1 (K 0..63)
    half8 wh[4][4];                   // kt 2..5 (K 64..191)
#pragma unroll
    for (int ktx = 0; ktx < 2; ++ktx)
#pragma unroll
        for (int s = 0; s < 4; ++s)
            wx[ktx][s] = *(const half8*)(whi + (((w * 6 + ktx) * 4 + s) * 64 + l) * 8);
#pragma unroll
    for (int kth = 0; kth < 4; ++kth)
#pragma unroll
        for (int s = 0; s < 4; ++s)
            wh[kth][s] = *(const half8*)(whi + (((w * 6 + 2 + kth) * 4 + s) * 64 + l) * 8);

    int jl = 16 * w + (l & 15);
    f32x4 bvec[4];
#pragma unroll
    for (int s = 0; s < 4; ++s) {
        float bv = biasv[s * 128 + jl];
        bvec[s] = (f32x4){bv, bv, bv, bv};
    }

    int arow = l & 15;
    int g16  = (l >> 4) * 16;
    uint rowbase = (uint)arow * (LROW * 2);
    uint rswz    = (uint)(arow & 7) << 4;
    int hrow0 = (l >> 4) * 4;

    // x staging address (byte offset within a plane), swizzled
    int xr = tid >> 5;
    uint xw = ((uint)xr * (LROW * 2) + (uint)(tid & 31) * 4) ^ ((uint)(xr & 7) << 4);

    // h write offsets for r=0..3 (byte offsets)
    uint hwa[4];
#pragma unroll
    for (int r = 0; r < 4; ++r) {
        uint row = (uint)(hrow0 + r);
        hwa[r] = (row * (LROW * 2) + 128u + 2u * (uint)jl) ^ ((row & 7u) << 4);
    }

    float cst[4]  = {0.f, 0.f, 0.f, 0.f};
    float hreg[4] = {0.f, 0.f, 0.f, 0.f};

    // zero LDS (h regions must read 0 at t=0)
    for (int i = tid; i < 2 * PLANE; i += 512) ((_Float16*)L)[i] = (_Float16)0.f;

    // prologue: x(0) staged into buf0, vx holds x(1)
    size_t xoff0 = (size_t)b0 * 64 + (size_t)tid * 2;
    uint vx = *(const uint*)(xhi + xoff0);
    __syncthreads();                       // zeros visible
    *(uint*)((char*)&L[0][0][0] + xw) = vx;
    vx = *(const uint*)(xhi + xoff0 + 65536);
    __syncthreads();                       // x(0) visible

    for (int t = 0; t < T_STEPS; ++t) {
        int p = t & 1;
        const char* ph = (const char*)&L[p][0][0];
        char* qh = (char*)&L[p ^ 1][0][0];

        // TOP of step: stage x(t+1) from regs; issue prefetch x(t+2) so it
        // has the whole step before the barrier's vmcnt drain.
        if (t < T_STEPS - 1) {
            *(uint*)(qh + xw) = vx;
            int tn = (t + 2 < T_STEPS) ? t + 2 : T_STEPS - 1;
            vx = *(const uint*)(xhi + xoff0 + (size_t)tn * 65536);
        }

        // A-fragments
        half8 ax0 = *(const half8*)(ph + ((rowbase + 0u   + g16) ^ rswz));
        half8 ax1 = *(const half8*)(ph + ((rowbase + 64u  + g16) ^ rswz));
        half8 ah0 = *(const half8*)(ph + ((rowbase + 128u + g16) ^ rswz));
        half8 ah1 = *(const half8*)(ph + ((rowbase + 192u + g16) ^ rswz));
        half8 ah2 = *(const half8*)(ph + ((rowbase + 256u + g16) ^ rswz));
        half8 ah3 = *(const half8*)(ph + ((rowbase + 320u + g16) ^ rswz));

        // single acc chain per gate, seeded by bias as C operand (no movs)
        f32x4 acc[4];
#pragma unroll
        for (int s = 0; s < 4; ++s) acc[s] = MF16(ax0, wx[0][s], bvec[s]);
#pragma unroll
        for (int s = 0; s < 4; ++s) acc[s] = MF16(ax1, wx[1][s], acc[s]);
#pragma unroll
        for (int s = 0; s < 4; ++s) acc[s] = MF16(ah0, wh[0][s], acc[s]);
#pragma unroll
        for (int s = 0; s < 4; ++s) acc[s] = MF16(ah1, wh[1][s], acc[s]);
#pragma unroll
        for (int s = 0; s < 4; ++s) acc[s] = MF16(ah2, wh[2][s], acc[s]);
#pragma unroll
        for (int s = 0; s < 4; ++s) acc[s] = MF16(ah3, wh[3][s], acc[s]);

        // pointwise LSTM cell (lane-local), exp2-folded + rcp-merged:
        //  Ei=e^-i, Ef=e^-f, Eg=e^-2g, Eo=e^-o (folded into W/bias)
        //  sig(i)*tanh(g) = (1-Eg)*rcp((1+Ei)(1+Eg))
        //  sig(o)*tanh(c) = (1-Ec)*rcp((1+Eo)(1+Ec)), Ec=e^-2c
#pragma unroll
        for (int r = 0; r < 4; ++r) {
            float Ei = fexp2(acc[0][r]);
            float Ef = fexp2(acc[1][r]);
            float Eg = fexp2(acc[2][r]);
            float Eo = fexp2(acc[3][r]);
            float rf  = frcp(1.f + Ef);
            float rig = frcp((1.f + Ei) * (1.f + Eg));
            cst[r] = rf * cst[r] + (1.f - Eg) * rig;
            float Ec = fexp2(cst[r] * -2.8853900817779268f);
            float roc = frcp((1.f + Eo) * (1.f + Ec));
            hreg[r] = (1.f - Ec) * roc;
        }

        if (t < T_STEPS - 1) {
            // stage h(t) (f16, single plane) into next buffer
#pragma unroll
            for (int r = 0; r < 4; ++r)
                *(_Float16*)(qh + hwa[r]) = (_Float16)hreg[r];
            __syncthreads();
        }
    }

#pragma unroll
    for (int r = 0; r < 4; ++r)
        hfin[(size_t)(b0 + hrow0 + r) * 128 + jl] = hreg[r];
}

// ---------------------------------------------------------------------------
// post: per row: u=tanh(W1c@h); v=W2@u; res=W0@h+127v; LN; linear; tile 196x
// with float4 stores.
// ---------------------------------------------------------------------------
__global__ __launch_bounds__(128) void post_kernel(const char* __restrict__ wsb,
                                                   const float* __restrict__ ln_g,
                                                   const float* __restrict__ ln_b,
                                                   const float* __restrict__ lin_b,
                                                   float* __restrict__ out) {
    const float* hfinal = (const float*)(wsb + OFF_HFIN);
    const float* W1cT   = (const float*)(wsb + OFF_W1CT);
    const float* W2T    = (const float*)(wsb + OFF_W2T);
    const float* W0T    = (const float*)(wsb + OFF_W0T);
    const float* linWT  = (const float*)(wsb + OFF_LINWT);

    __shared__ float sh[128], su[128], sres[128], so_[128], spart[4];
    int b = blockIdx.x, f = threadIdx.x;

    sh[f] = hfinal[(size_t)b * 128 + f];
    __syncthreads();

    float acc = 0.f;
#pragma unroll 4
    for (int k = 0; k < 128; ++k) acc += W1cT[k * 128 + f] * sh[k];
    su[f] = tanhf_fast(acc);
    __syncthreads();

    float v = 0.f, r0 = 0.f;
#pragma unroll 4
    for (int k = 0; k < 128; ++k) {
        v  += W2T[k * 128 + f] * su[k];
        r0 += W0T[k * 128 + f] * sh[k];
    }
    float res = r0 + 127.f * v;

    int lane = f & 63, wid = f >> 6;
    float s = res;
#pragma unroll
    for (int off = 32; off > 0; off >>= 1) s += __shfl_down(s, off);
    if (lane == 0) spart[wid] = s;
    __syncthreads();
    float mu = (spart[0] + spart[1]) * (1.f / 128.f);
    float d = res - mu;
    float s2 = d * d;
#pragma unroll
    for (int off = 32; off > 0; off >>= 1) s2 += __shfl_down(s2, off);
    if (lane == 0) spart[2 + wid] = s2;
    __syncthreads();
    float var = (spart[2] + spart[3]) * (1.f / 128.f);
    float rn = d * rsqrtf(var + 1e-5f) * ln_g[f] + ln_b[f];
    sres[f] = rn;
    __syncthreads();

    float o = lin_b[f];
#pragma unroll 4
    for (int k = 0; k < 128; ++k) o += linWT[k * 128 + f] * sres[k];
    so_[f] = o;
    __syncthreads();

    // tile to (14,14): 196*128 f32 = 6272 float4 per row b
    float4 val = *(const float4*)&so_[(f & 31) << 2];
    float4* op4 = (float4*)(out + (size_t)b * 25088);
#pragma unroll 7
    for (int i = 0; i < 49; ++i) op4[i * 128 + f] = val;
}

// ---------------------------------------------------------------------------
extern "C" void kernel_launch(void* const* d_in, const int* in_sizes, int n_in,
                              void* d_out, int out_size, void* d_ws, size_t ws_size,
                              hipStream_t stream) {
    const float* x      = (const float*)d_in[0];
    const float* conv_w = (const float*)d_in[1];
    const float* conv_b = (const float*)d_in[2];
    const float* w_ih   = (const float*)d_in[3];
    const float* w_hh   = (const float*)d_in[4];
    const float* b_ih   = (const float*)d_in[5];
    const float* b_hh   = (const float*)d_in[6];
    const float* W1     = (const float*)d_in[7];
    const float* W2     = (const float*)d_in[8];
    const float* W0     = (const float*)d_in[9];
    const float* ln_g   = (const float*)d_in[10];
    const float* ln_b   = (const float*)d_in[11];
    const float* lin_w  = (const float*)d_in[12];
    const float* lin_b  = (const float*)d_in[13];
    char* wsb  = (char*)d_ws;
    float* out = (float*)d_out;

    prep_conv_kernel<<<dim3(1345), dim3(512), 0, stream>>>(w_ih, w_hh, b_ih, b_hh,
                                                           W1, W2, W0, lin_w,
                                                           x, conv_w, conv_b, wsb);
    lstm_mfma<<<dim3(64), dim3(512), 0, stream>>>(wsb, wsb);
    post_kernel<<<dim3(1024), dim3(128), 0, stream>>>(wsb, ln_g, ln_b, lin_b, out);
}